// Round 1
// baseline (111.032 us; speedup 1.0000x reference)
//
#include <hip/hip_runtime.h>
#include <hip/hip_bf16.h>
#include <stdint.h>

// Problem constants
#define BB 64     // batch
#define LL 256    // x seq len
#define TT 64     // y seq len
#define DD 512    // input dim
#define EE 200    // embed dim
#define EP 224    // embed dim padded to 7*32 for MFMA K
#define YSTRIDE 232  // LDS row stride (shorts) to break bank conflicts (464B, 16B-aligned)

typedef __attribute__((ext_vector_type(8))) short short8;
typedef __attribute__((ext_vector_type(4))) float floatx4;
typedef __attribute__((ext_vector_type(4))) int intx4;

__device__ __forceinline__ short f2bf(float f) {
  uint32_t u = __builtin_bit_cast(uint32_t, f);
  u = (u + 0x7fffu + ((u >> 16) & 1u)) >> 16;  // RNE
  return (short)u;
}

// ---------------- Kernel 0: W (200x512 f32) -> Wb (224x512 bf16, zero-padded rows)
__global__ void wcvt_kernel(const float* __restrict__ W, short* __restrict__ Wb) {
  int idx = blockIdx.x * 256 + threadIdx.x;   // 0 .. 224*512-1
  int e = idx >> 9;
  int k = idx & 511;
  float v = (e < EE) ? W[e * DD + k] : 0.0f;
  Wb[idx] = f2bf(v);
}

// ---------------- Kernel 1: projection  out[r][e] = sum_k in[r][k]*W[e][k] + b[e]
// Block: 256 thr = 4 waves; each wave does 16 rows x 224 cols; block = 64 rows.
__global__ __launch_bounds__(256) void proj_kernel(const float* __restrict__ in,
                                                   const short* __restrict__ Wb,
                                                   const float* __restrict__ bias,
                                                   short* __restrict__ out) {
  const int tid  = threadIdx.x;
  const int lane = tid & 63;
  const int wid  = tid >> 6;
  const int r16   = lane & 15;
  const int khalf = lane >> 4;          // 0..3
  const int rowbase = blockIdx.x * 64 + wid * 16;

  floatx4 acc[14];
#pragma unroll
  for (int n = 0; n < 14; n++) acc[n] = (floatx4){0.f, 0.f, 0.f, 0.f};

  const float* arow = in + (size_t)(rowbase + r16) * DD + khalf * 8;

  for (int kk = 0; kk < 16; kk++) {     // K = 512 = 16 * 32
    const floatx4* ap = (const floatx4*)(arow + kk * 32);
    floatx4 a0 = ap[0];
    floatx4 a1 = ap[1];
    short8 afrag;
    afrag[0] = f2bf(a0.x); afrag[1] = f2bf(a0.y);
    afrag[2] = f2bf(a0.z); afrag[3] = f2bf(a0.w);
    afrag[4] = f2bf(a1.x); afrag[5] = f2bf(a1.y);
    afrag[6] = f2bf(a1.z); afrag[7] = f2bf(a1.w);
#pragma unroll
    for (int n = 0; n < 14; n++) {
      const short8 wfrag = *(const short8*)(Wb + (size_t)(n * 16 + r16) * DD + kk * 32 + khalf * 8);
      acc[n] = __builtin_amdgcn_mfma_f32_16x16x32_bf16(afrag, wfrag, acc[n], 0, 0, 0);
    }
  }

  // Epilogue: C/D layout col = lane&15 (e), row = (lane>>4)*4 + reg (x-row)
  const int orow = rowbase + khalf * 4;
#pragma unroll
  for (int n = 0; n < 14; n++) {
    const int e = n * 16 + r16;
    const float bv = (e < EE) ? bias[e] : 0.0f;  // pad cols: acc==0, bv==0 -> store 0
#pragma unroll
    for (int r = 0; r < 4; r++) {
      out[(size_t)(orow + r) * EP + e] = f2bf(acc[n][r] + bv);
    }
  }
}

// ---------------- Kernel 2: pair kernel
// Block handles (i, j0, j0+1). 4 waves; wave w: L-rows [w*64, w*64+64) x all 64 t x 2 j.
// Fused: colmax over L, mean over T.
__global__ __launch_bounds__(256) void pair_kernel(const short* __restrict__ xp,
                                                   const short* __restrict__ yp,
                                                   float* __restrict__ S) {
  __shared__ short ylds[2][TT][YSTRIDE];
  __shared__ float red[4][2][TT];

  const int tid  = threadIdx.x;
  const int lane = tid & 63;
  const int wid  = tid >> 6;
  const int bid  = blockIdx.x;
  const int i  = bid >> 5;
  const int j0 = (bid & 31) * 2;

  // Stage yp[j0] and yp[j0+1] into LDS (64 rows x 224 shorts each, 16B chunks)
#pragma unroll
  for (int jj = 0; jj < 2; jj++) {
    const intx4* src = (const intx4*)(yp + (size_t)(j0 + jj) * TT * EP);
    for (int c = tid; c < TT * 28; c += 256) {   // 28 = 224/8 shorts per 16B
      int row = c / 28, ch = c % 28;
      *(intx4*)&ylds[jj][row][ch * 8] = src[row * 28 + ch];
    }
  }
  __syncthreads();

  const int r16   = lane & 15;
  const int khalf = lane >> 4;

  floatx4 acc[2][4][4];
#pragma unroll
  for (int jj = 0; jj < 2; jj++)
#pragma unroll
    for (int m = 0; m < 4; m++)
#pragma unroll
      for (int n = 0; n < 4; n++) acc[jj][m][n] = (floatx4){0.f, 0.f, 0.f, 0.f};

  const short* abase = xp + ((size_t)i * LL + wid * 64 + r16) * EP + khalf * 8;

  for (int kk = 0; kk < 7; kk++) {      // K = 224 = 7 * 32
    short8 a[4];
#pragma unroll
    for (int m = 0; m < 4; m++)
      a[m] = *(const short8*)(abase + (size_t)m * 16 * EP + kk * 32);
#pragma unroll
    for (int jj = 0; jj < 2; jj++) {
#pragma unroll
      for (int n = 0; n < 4; n++) {
        const short8 bfrag = *(const short8*)&ylds[jj][n * 16 + r16][kk * 32 + khalf * 8];
#pragma unroll
        for (int m = 0; m < 4; m++)
          acc[jj][m][n] = __builtin_amdgcn_mfma_f32_16x16x32_bf16(a[m], bfrag, acc[jj][m][n], 0, 0, 0);
      }
    }
  }

  // Reduce: max over this wave's 64 L-rows per column t.
  // C layout: col t = n*16 + (lane&15); rows live in (lane>>4)*4 + reg across m.
#pragma unroll
  for (int jj = 0; jj < 2; jj++) {
#pragma unroll
    for (int n = 0; n < 4; n++) {
      float v = acc[jj][0][n][0];
#pragma unroll
      for (int m = 0; m < 4; m++)
#pragma unroll
        for (int r = 0; r < 4; r++) v = fmaxf(v, acc[jj][m][n][r]);
      v = fmaxf(v, __shfl_xor(v, 16, 64));
      v = fmaxf(v, __shfl_xor(v, 32, 64));
      if (lane < 16) red[wid][jj][n * 16 + lane] = v;
    }
  }
  __syncthreads();

  // Final: max across 4 waves, then mean over t (64 lanes = 64 t), two waves for two j.
  if (tid < 128) {
    const int jj = tid >> 6;
    const int t  = tid & 63;
    float v = fmaxf(fmaxf(red[0][jj][t], red[1][jj][t]),
                    fmaxf(red[2][jj][t], red[3][jj][t]));
    v += __shfl_xor(v, 1, 64);
    v += __shfl_xor(v, 2, 64);
    v += __shfl_xor(v, 4, 64);
    v += __shfl_xor(v, 8, 64);
    v += __shfl_xor(v, 16, 64);
    v += __shfl_xor(v, 32, 64);
    if (t == 0) S[i * BB + j0 + jj] = v * (1.0f / 64.0f);
  }
}

extern "C" void kernel_launch(void* const* d_in, const int* in_sizes, int n_in,
                              void* d_out, int out_size, void* d_ws, size_t ws_size,
                              hipStream_t stream) {
  const float* x = (const float*)d_in[0];   // 64*256*512
  const float* y = (const float*)d_in[1];   // 64*64*512
  const float* W = (const float*)d_in[2];   // 200*512
  const float* b = (const float*)d_in[3];   // 200
  float* S = (float*)d_out;                 // 64*64

  char* ws = (char*)d_ws;
  short* Wb = (short*)ws;                              // 224*512*2   = 229,376 B
  short* xp = (short*)(ws + 262144);                   // 16384*224*2 = 7,340,032 B
  short* yp = (short*)(ws + 262144 + 7340032);         // 4096*224*2  = 1,835,008 B

  wcvt_kernel<<<448, 256, 0, stream>>>(W, Wb);
  proj_kernel<<<256, 256, 0, stream>>>(x, Wb, b, xp);  // 16384 rows
  proj_kernel<<<64,  256, 0, stream>>>(y, Wb, b, yp);  // 4096 rows
  pair_kernel<<<2048, 256, 0, stream>>>(xp, yp, S);
}